// Round 1
// baseline (6500.292 us; speedup 1.0000x reference)
//
#include <hip/hip_runtime.h>
#include <hip/hip_bf16.h>
#include <stdint.h>

typedef unsigned short u16;
typedef __attribute__((ext_vector_type(8))) short bh8;
typedef __attribute__((ext_vector_type(4))) float f32x4;

static constexpr int Bv = 8, Tv = 2048, Cv = 1024;

__device__ inline u16 f2bf(float f) {
    unsigned u;
    __builtin_memcpy(&u, &f, 4);
    u = (u + 0x7fffu + ((u >> 16) & 1u)) >> 16;
    return (u16)u;
}
__device__ inline float bf2f(u16 v) {
    unsigned u = ((unsigned)v) << 16;
    float f;
    __builtin_memcpy(&f, &u, 4);
    return f;
}

// ---------------- elementwise convert x (fp32 -> bf16) ----------------
__global__ void cvt_x(const float* __restrict__ x, u16* __restrict__ xb, int n4) {
    int i = blockIdx.x * blockDim.x + threadIdx.x;
    if (i < n4) {
        float4 v = ((const float4*)x)[i];
        ushort4 o;
        o.x = f2bf(v.x); o.y = f2bf(v.y); o.z = f2bf(v.z); o.w = f2bf(v.w);
        ((ushort4*)xb)[i] = o;
    }
}

// ------------- transpose + convert 1024x1024 fp32 -> bf16 [n][k] -------------
__global__ void transpose_cvt(const float* __restrict__ W, u16* __restrict__ WT) {
    __shared__ float tile[32][33];
    int kb = blockIdx.x * 32, nb = blockIdx.y * 32;
    int tx = threadIdx.x, ty = threadIdx.y; // block (32,8)
#pragma unroll
    for (int r = 0; r < 32; r += 8)
        tile[ty + r][tx] = W[(size_t)(kb + ty + r) * 1024 + nb + tx];
    __syncthreads();
#pragma unroll
    for (int r = 0; r < 32; r += 8)
        WT[(size_t)(nb + ty + r) * 1024 + kb + tx] = f2bf(tile[tx][ty + r]);
}

// ---------------- bf16 MFMA GEMM: C[M,N] = A[M,K] * B[K,N], B given as BT[N,K] ----------------
template <bool OUT_BF16>
__global__ __launch_bounds__(256, 2) void gemm_bt(const u16* __restrict__ A,
                                                  const u16* __restrict__ BT,
                                                  void* __restrict__ Cout,
                                                  int M, int N, int K) {
    __shared__ uint4 As[2][1024]; // [row 0..127][slot 0..7] 16B granules, slot XOR-swizzled
    __shared__ uint4 Bs[2][1024];
    const int tid = threadIdx.x;
    const int lane = tid & 63;
    const int w = tid >> 6, wm = w >> 1, wn = w & 1;
    const int nTN = N >> 7;
    const int nwg = gridDim.x;
    const int q = nwg >> 3; // grid divisible by 8
    const int bid = blockIdx.x;
    const int swz = (bid & 7) * q + (bid >> 3); // XCD-contiguous chunks
    const int tm = swz / nTN, tn = swz % nTN;
    const size_t row0 = (size_t)tm * 128;
    const size_t col0 = (size_t)tn * 128;
    const int KT = K >> 6;

    uint4 ra[4], rb[4];

    auto issue_loads = [&](int kt) {
#pragma unroll
        for (int p = 0; p < 4; ++p) {
            int gi = p * 256 + tid;
            int r = gi >> 3, sl = gi & 7;
            ra[p] = *(const uint4*)(A + (row0 + r) * K + (size_t)kt * 64 + sl * 8);
            rb[p] = *(const uint4*)(BT + (col0 + r) * K + (size_t)kt * 64 + sl * 8);
        }
    };
    auto write_lds = [&](int bi) {
#pragma unroll
        for (int p = 0; p < 4; ++p) {
            int gi = p * 256 + tid;
            int r = gi >> 3, sl = gi & 7;
            int ph = sl ^ (r & 7);
            As[bi][r * 8 + ph] = ra[p];
            Bs[bi][r * 8 + ph] = rb[p];
        }
    };

    f32x4 acc[4][4];
#pragma unroll
    for (int m = 0; m < 4; ++m)
#pragma unroll
        for (int n = 0; n < 4; ++n)
            acc[m][n] = f32x4{0.f, 0.f, 0.f, 0.f};

    issue_loads(0);
    write_lds(0);
    int cur = 0;
    for (int kt = 0; kt < KT; ++kt) {
        if (kt + 1 < KT) issue_loads(kt + 1);
        __syncthreads();
#pragma unroll
        for (int s = 0; s < 2; ++s) {
            bh8 af[4], bfv[4];
#pragma unroll
            for (int m = 0; m < 4; ++m) {
                int ar = wm * 64 + m * 16 + (lane & 15);
                int sl = (s * 4 + (lane >> 4)) ^ (ar & 7);
                af[m] = __builtin_bit_cast(bh8, As[cur][ar * 8 + sl]);
            }
#pragma unroll
            for (int n = 0; n < 4; ++n) {
                int br = wn * 64 + n * 16 + (lane & 15);
                int sl = (s * 4 + (lane >> 4)) ^ (br & 7);
                bfv[n] = __builtin_bit_cast(bh8, Bs[cur][br * 8 + sl]);
            }
#pragma unroll
            for (int m = 0; m < 4; ++m)
#pragma unroll
                for (int n = 0; n < 4; ++n)
                    acc[m][n] = __builtin_amdgcn_mfma_f32_16x16x32_bf16(af[m], bfv[n], acc[m][n], 0, 0, 0);
        }
        if (kt + 1 < KT) write_lds(cur ^ 1);
        cur ^= 1;
    }
    // epilogue: D elem (row=(lane>>4)*4+r, col=lane&15) per 16x16 frag
#pragma unroll
    for (int m = 0; m < 4; ++m) {
#pragma unroll
        for (int n = 0; n < 4; ++n) {
#pragma unroll
            for (int r = 0; r < 4; ++r) {
                size_t row = row0 + wm * 64 + m * 16 + (lane >> 4) * 4 + r;
                size_t col = col0 + wn * 64 + n * 16 + (lane & 15);
                float v = acc[m][n][r];
                if (OUT_BF16)
                    ((u16*)Cout)[row * N + col] = f2bf(v);
                else
                    ((float*)Cout)[row * N + col] = v;
            }
        }
    }
}

// ---------------- sequential CfC scan ----------------
// 256 blocks x 1024 threads (cooperative). block = (batch b = bid&7, col-group g = bid>>3).
// Each block owns cols [g*32, g*32+32) of both f and g gates. Recurrent weights fp32 in VGPRs.
// h state exchanged via global double-buffer with agent-scope atomics + per-block flags.
__global__ __launch_bounds__(1024, 4) void cfc_scan(const float* __restrict__ Wf,
                                                    const float* __restrict__ Wg,
                                                    const u16* __restrict__ Pf,
                                                    const u16* __restrict__ Pg,
                                                    u16* __restrict__ H,
                                                    float* hbuf, int* flags) {
    const int bidx = blockIdx.x;
    const int b = bidx & 7, g = bidx >> 3;
    const int tid = threadIdx.x;
    const int col_local = tid >> 4; // 0..63 (0..31 = f-gate cols, 32..63 = g-gate cols)
    const int sub = tid & 15;      // 64-element K-chunk owner
    const bool isF = col_local < 32;
    const int colg = g * 32 + (col_local & 31);

    float wreg[64];
    {
        const float* Wsel = isF ? Wf : Wg;
#pragma unroll
        for (int j = 0; j < 64; ++j)
            wreg[j] = Wsel[(size_t)(1024 + sub * 64 + j) * 1024 + colg];
    }
    const u16* Psel = isF ? Pf : Pg;
    const size_t prow_base = ((size_t)b * Tv) * Cv + colg;

    __shared__ __align__(16) float hs[1024]; // swizzled h_t staging
    __shared__ float fgbuf[64];

    int* fl = flags + b * 32;

    for (int t = 0; t < Tv; ++t) {
        float p = 0.f;
        if (sub == 0) p = bf2f(Psel[prow_base + (size_t)t * Cv]); // hoisted x-part, early load
        // ---- 1. wait for all 32 producers of batch b to publish h_t ----
        if (tid < 64) {
            while (true) {
                int f = __hip_atomic_load(&fl[tid & 31], __ATOMIC_RELAXED, __HIP_MEMORY_SCOPE_AGENT);
                if (__all(f >= t)) break;
                __builtin_amdgcn_s_sleep(1);
            }
        }
        __syncthreads();
        // ---- 2. stage h_t (fp32, L3-coherent loads) into swizzled LDS ----
        if (tid < 512) {
            double d = __hip_atomic_load((double*)(hbuf + ((size_t)(t & 1) * Bv + b) * Cv) + tid,
                                         __ATOMIC_RELAXED, __HIP_MEMORY_SCOPE_AGENT);
            float2 v = __builtin_bit_cast(float2, d);
            int sw = tid >> 5;   // 64-elem chunk
            int pr = tid & 31;   // float2 pair within chunk
            int slot = pr >> 1;  // 16B slot
            int base = sw * 64 + ((slot ^ (sw & 7)) << 2) + ((pr & 1) << 1);
            hs[base] = v.x;
            hs[base + 1] = v.y;
        }
        __syncthreads();
        // ---- 3. fp32 matvec partials: thread (col,sub) does 64 MACs ----
        float acc = 0.f;
#pragma unroll
        for (int s5 = 0; s5 < 16; ++s5) {
            int slot = s5 ^ (sub & 7);
            float4 hv = *(const float4*)&hs[sub * 64 + slot * 4];
            acc = fmaf(hv.x, wreg[s5 * 4 + 0], acc);
            acc = fmaf(hv.y, wreg[s5 * 4 + 1], acc);
            acc = fmaf(hv.z, wreg[s5 * 4 + 2], acc);
            acc = fmaf(hv.w, wreg[s5 * 4 + 3], acc);
        }
        acc += __shfl_xor(acc, 8, 16);
        acc += __shfl_xor(acc, 4, 16);
        acc += __shfl_xor(acc, 2, 16);
        acc += __shfl_xor(acc, 1, 16);
        if (sub == 0) {
            float u = acc + p;
            float r;
            if (isF) r = 1.f / (1.f + __expf(-u));        // sigmoid
            else     r = 2.f / (1.f + __expf(-2.f * u)) - 1.f; // tanh
            fgbuf[col_local] = r;
        }
        __syncthreads();
        // ---- 4. finalize (wave0 lanes 0..31): h_new = f*h + (1-f)*g ----
        if (tid < 32) {
            float f = fgbuf[tid];
            float gv = fgbuf[32 + tid];
            int i = g * 32 + tid;
            int sw = i >> 6;
            int e = i & 63;
            float h_old = hs[sw * 64 + (((e >> 2) ^ (sw & 7)) << 2) + (e & 3)];
            float hnew = fmaf(f, h_old - gv, gv);
            H[((size_t)b * Tv + t) * Cv + i] = f2bf(hnew);
            __hip_atomic_store(hbuf + ((size_t)((t + 1) & 1) * Bv + b) * Cv + i, hnew,
                               __ATOMIC_RELAXED, __HIP_MEMORY_SCOPE_AGENT);
        }
        if (tid < 64) {
            asm volatile("s_waitcnt vmcnt(0)" ::: "memory"); // h stores globally visible
            if (tid == 0)
                __hip_atomic_store(&fl[g], t + 1, __ATOMIC_RELAXED, __HIP_MEMORY_SCOPE_AGENT);
        }
    }
}

// ---------------- host launch ----------------
extern "C" void kernel_launch(void* const* d_in, const int* in_sizes, int n_in,
                              void* d_out, int out_size, void* d_ws, size_t ws_size,
                              hipStream_t stream) {
    const float* x  = (const float*)d_in[0];
    const float* Wf = (const float*)d_in[1];
    const float* Wg = (const float*)d_in[2];
    const float* Wp = (const float*)d_in[3];
    float* out = (float*)d_out;
    char* ws = (char*)d_ws;

    // workspace layout (bytes)
    u16*   xb    = (u16*)(ws + 0);          // 33554432
    u16*   Pf    = (u16*)(ws + 33554432);   // 33554432
    u16*   Pg    = (u16*)(ws + 67108864);   // 33554432
    u16*   Hb    = (u16*)(ws + 100663296);  // 33554432
    u16*   WfT   = (u16*)(ws + 134217728);  // 2097152
    u16*   WgT   = (u16*)(ws + 136314880);  // 2097152
    u16*   WpT   = (u16*)(ws + 138412032);  // 2097152
    float* hbuf  = (float*)(ws + 140509184); // 65536 (2 x 8 x 1024 fp32)
    int*   flags = (int*)(ws + 140574720);   // 1024 (8 x 32)

    // zero h_0 double-buffer + flags (contiguous region)
    hipMemsetAsync(hbuf, 0, 65536 + 4096, stream);

    cvt_x<<<16384, 256, 0, stream>>>(x, xb, (Bv * Tv * Cv) / 4);

    dim3 tg(32, 32), tb(32, 8);
    transpose_cvt<<<tg, tb, 0, stream>>>(Wf, WfT); // top half rows 0..1024 of W_f
    transpose_cvt<<<tg, tb, 0, stream>>>(Wg, WgT);
    transpose_cvt<<<tg, tb, 0, stream>>>(Wp, WpT);

    gemm_bt<true><<<1024, 256, 0, stream>>>(xb, WfT, (void*)Pf, Bv * Tv, Cv, Cv);
    gemm_bt<true><<<1024, 256, 0, stream>>>(xb, WgT, (void*)Pg, Bv * Tv, Cv, Cv);

    {
        const float* a0 = Wf;
        const float* a1 = Wg;
        const u16* a2 = Pf;
        const u16* a3 = Pg;
        u16* a4 = Hb;
        float* a5 = hbuf;
        int* a6 = flags;
        void* args[] = {(void*)&a0, (void*)&a1, (void*)&a2, (void*)&a3,
                        (void*)&a4, (void*)&a5, (void*)&a6};
        hipLaunchCooperativeKernel((const void*)cfc_scan, dim3(256), dim3(1024), args, 0, stream);
    }

    gemm_bt<false><<<1024, 256, 0, stream>>>(Hb, WpT, (void*)out, Bv * Tv, Cv, Cv);
}

// Round 2
// 4366.106 us; speedup vs baseline: 1.4888x; 1.4888x over previous
//
#include <hip/hip_runtime.h>
#include <hip/hip_bf16.h>
#include <stdint.h>

typedef unsigned short u16;
typedef __attribute__((ext_vector_type(8))) short bh8;
typedef __attribute__((ext_vector_type(4))) float f32x4;

static constexpr int Bv = 8, Tv = 2048, Cv = 1024;
#define SENT_BITS 0x7F800000u  // +inf: impossible h value since |h| < 1 strictly

__device__ inline u16 f2bf(float f) {
    unsigned u;
    __builtin_memcpy(&u, &f, 4);
    u = (u + 0x7fffu + ((u >> 16) & 1u)) >> 16;
    return (u16)u;
}
__device__ inline float bf2f(u16 v) {
    unsigned u = ((unsigned)v) << 16;
    float f;
    __builtin_memcpy(&f, &u, 4);
    return f;
}

// ---------------- elementwise convert x (fp32 -> bf16) ----------------
__global__ void cvt_x(const float* __restrict__ x, u16* __restrict__ xb, int n4) {
    int i = blockIdx.x * blockDim.x + threadIdx.x;
    if (i < n4) {
        float4 v = ((const float4*)x)[i];
        ushort4 o;
        o.x = f2bf(v.x); o.y = f2bf(v.y); o.z = f2bf(v.z); o.w = f2bf(v.w);
        ((ushort4*)xb)[i] = o;
    }
}

// ------------- transpose + convert 1024x1024 fp32 -> bf16 [n][k] -------------
__global__ void transpose_cvt(const float* __restrict__ W, u16* __restrict__ WT) {
    __shared__ float tile[32][33];
    int kb = blockIdx.x * 32, nb = blockIdx.y * 32;
    int tx = threadIdx.x, ty = threadIdx.y; // block (32,8)
#pragma unroll
    for (int r = 0; r < 32; r += 8)
        tile[ty + r][tx] = W[(size_t)(kb + ty + r) * 1024 + nb + tx];
    __syncthreads();
#pragma unroll
    for (int r = 0; r < 32; r += 8)
        WT[(size_t)(nb + ty + r) * 1024 + kb + tx] = f2bf(tile[tx][ty + r]);
}

// ---------------- bf16 MFMA GEMM: C[M,N] = A[M,K] * B[K,N], B given as BT[N,K] ----------------
template <bool OUT_BF16>
__global__ __launch_bounds__(256, 2) void gemm_bt(const u16* __restrict__ A,
                                                  const u16* __restrict__ BT,
                                                  void* __restrict__ Cout,
                                                  int M, int N, int K) {
    __shared__ uint4 As[2][1024]; // [row 0..127][slot 0..7] 16B granules, slot XOR-swizzled
    __shared__ uint4 Bs[2][1024];
    const int tid = threadIdx.x;
    const int lane = tid & 63;
    const int w = tid >> 6, wm = w >> 1, wn = w & 1;
    const int nTN = N >> 7;
    const int nwg = gridDim.x;
    const int q = nwg >> 3; // grid divisible by 8
    const int bid = blockIdx.x;
    const int swz = (bid & 7) * q + (bid >> 3); // XCD-contiguous chunks
    const int tm = swz / nTN, tn = swz % nTN;
    const size_t row0 = (size_t)tm * 128;
    const size_t col0 = (size_t)tn * 128;
    const int KT = K >> 6;

    uint4 ra[4], rb[4];

    auto issue_loads = [&](int kt) {
#pragma unroll
        for (int p = 0; p < 4; ++p) {
            int gi = p * 256 + tid;
            int r = gi >> 3, sl = gi & 7;
            ra[p] = *(const uint4*)(A + (row0 + r) * K + (size_t)kt * 64 + sl * 8);
            rb[p] = *(const uint4*)(BT + (col0 + r) * K + (size_t)kt * 64 + sl * 8);
        }
    };
    auto write_lds = [&](int bi) {
#pragma unroll
        for (int p = 0; p < 4; ++p) {
            int gi = p * 256 + tid;
            int r = gi >> 3, sl = gi & 7;
            int ph = sl ^ (r & 7);
            As[bi][r * 8 + ph] = ra[p];
            Bs[bi][r * 8 + ph] = rb[p];
        }
    };

    f32x4 acc[4][4];
#pragma unroll
    for (int m = 0; m < 4; ++m)
#pragma unroll
        for (int n = 0; n < 4; ++n)
            acc[m][n] = f32x4{0.f, 0.f, 0.f, 0.f};

    issue_loads(0);
    write_lds(0);
    int cur = 0;
    for (int kt = 0; kt < KT; ++kt) {
        if (kt + 1 < KT) issue_loads(kt + 1);
        __syncthreads();
#pragma unroll
        for (int s = 0; s < 2; ++s) {
            bh8 af[4], bfv[4];
#pragma unroll
            for (int m = 0; m < 4; ++m) {
                int ar = wm * 64 + m * 16 + (lane & 15);
                int sl = (s * 4 + (lane >> 4)) ^ (ar & 7);
                af[m] = __builtin_bit_cast(bh8, As[cur][ar * 8 + sl]);
            }
#pragma unroll
            for (int n = 0; n < 4; ++n) {
                int br = wn * 64 + n * 16 + (lane & 15);
                int sl = (s * 4 + (lane >> 4)) ^ (br & 7);
                bfv[n] = __builtin_bit_cast(bh8, Bs[cur][br * 8 + sl]);
            }
#pragma unroll
            for (int m = 0; m < 4; ++m)
#pragma unroll
                for (int n = 0; n < 4; ++n)
                    acc[m][n] = __builtin_amdgcn_mfma_f32_16x16x32_bf16(af[m], bfv[n], acc[m][n], 0, 0, 0);
        }
        if (kt + 1 < KT) write_lds(cur ^ 1);
        cur ^= 1;
    }
#pragma unroll
    for (int m = 0; m < 4; ++m) {
#pragma unroll
        for (int n = 0; n < 4; ++n) {
#pragma unroll
            for (int r = 0; r < 4; ++r) {
                size_t row = row0 + wm * 64 + m * 16 + (lane >> 4) * 4 + r;
                size_t col = col0 + wn * 64 + n * 16 + (lane & 15);
                float v = acc[m][n][r];
                if (OUT_BF16)
                    ((u16*)Cout)[row * N + col] = f2bf(v);
                else
                    ((float*)Cout)[row * N + col] = v;
            }
        }
    }
}

// ---------------- init h triple-buffer: buf0 = h0 = 0, buf1/buf2 = sentinel ----------------
__global__ void init_hbuf(unsigned* hbuf) {
    int i = blockIdx.x * 1024 + threadIdx.x; // 24 blocks x 1024 = 24576 words
    hbuf[i] = (i < 8192) ? 0u : SENT_BITS;
}

// ---------------- sequential CfC scan (sentinel-poll, triple-buffered h) ----------------
// 256 blocks x 1024 threads cooperative. block = (batch b = bid&7, col-group g = bid>>3).
// Wave w of a block owns h-cols {g*32+2w, g*32+2w+1}; its 4 16-lane slots compute
// {f(c0), g(c0), f(c1), g(c1)}. Recurrent weights fp32 in VGPRs (64/thread).
// h exchanged via global fp32 triple-buffer; consumers poll data words against +inf
// sentinel (h can never be inf since |h|<1). One L3 one-way trip per step.
__global__ __launch_bounds__(1024, 4) void cfc_scan(const float* __restrict__ Wf,
                                                    const float* __restrict__ Wg,
                                                    const u16* __restrict__ Pf,
                                                    const u16* __restrict__ Pg,
                                                    u16* __restrict__ H,
                                                    float* hbuf) {
    const int bidx = blockIdx.x;
    const int b = bidx & 7, g = bidx >> 3;
    const int tid = threadIdx.x;
    const int w = tid >> 6;
    const int lane = tid & 63;
    const int slot = lane >> 4; // 0..3
    const int sub = lane & 15;  // k-chunk owner within slot
    const int col = g * 32 + 2 * w + (slot >> 1);
    const bool isG = (slot & 1) != 0;

    // wreg[s5*4+e] = Wsel[1024 + (s5*64 + sub*4 + e)][col]  (recurrent half of W)
    float wreg[64];
    {
        const float* Wsel = isG ? Wg : Wf;
#pragma unroll
        for (int j = 0; j < 64; ++j) {
            int k = (j >> 2) * 64 + sub * 4 + (j & 3);
            wreg[j] = Wsel[(size_t)(1024 + k) * 1024 + col];
        }
    }
    const u16* Psel = isG ? Pg : Pf;
    const size_t prow = (size_t)b * Tv * Cv + col;

    __shared__ __align__(16) float hs[1024];

    float* hb = hbuf + (size_t)b * 1024; // + buf*8192 selects buffer
    int bc = 0, bn = 1, bx = 2;          // consume / publish / clear (t, t+1, t+2 mod 3)

    for (int t = 0; t < Tv; ++t) {
        // prefetch hoisted x-part early (hidden under poll)
        float p = 0.f;
        if (sub == 0) p = bf2f(Psel[prow + (size_t)t * Cv]);
        __syncthreads(); // hs from previous step fully consumed
        // ---- poll + stage: each thread polls its own word (the poll IS the load) ----
        {
            const unsigned* src = (const unsigned*)(hb + (size_t)bc * 8192) + tid;
            unsigned v;
            do {
                v = __hip_atomic_load(src, __ATOMIC_RELAXED, __HIP_MEMORY_SCOPE_AGENT);
            } while (v == SENT_BITS);
            hs[tid] = __builtin_bit_cast(float, v);
        }
        __syncthreads();
        // ---- clear buffer bx (own 2 cols) for reuse at t+2; safe: everyone consumed
        // h_{t-1} (they published h_t which we just polled). Acked before our publish
        // via the per-wave vmcnt(0) below.
        if ((lane & 31) == 0)
            __hip_atomic_store((unsigned*)(hb + (size_t)bx * 8192 + col), SENT_BITS,
                               __ATOMIC_RELAXED, __HIP_MEMORY_SCOPE_AGENT);
        // ---- fp32 matvec: 64 FMA/thread, conflict-free LDS (256B contiguous per wave-read)
        float acc = 0.f;
#pragma unroll
        for (int s5 = 0; s5 < 16; ++s5) {
            float4 hv = *(const float4*)&hs[s5 * 64 + sub * 4];
            acc = fmaf(hv.x, wreg[s5 * 4 + 0], acc);
            acc = fmaf(hv.y, wreg[s5 * 4 + 1], acc);
            acc = fmaf(hv.z, wreg[s5 * 4 + 2], acc);
            acc = fmaf(hv.w, wreg[s5 * 4 + 3], acc);
        }
        acc += __shfl_xor(acc, 8);
        acc += __shfl_xor(acc, 4);
        acc += __shfl_xor(acc, 2);
        acc += __shfl_xor(acc, 1);
        float u_ = acc + p;
        float act;
        if (isG) {
            float au = fabsf(u_);
            float e = __expf(-2.f * au);
            float tv = (1.f - e) / (1.f + e);
            act = (u_ < 0.f) ? -tv : tv; // tanh
        } else {
            act = 1.f / (1.f + __expf(-u_)); // sigmoid
        }
        float other = __shfl_xor(act, 16); // pair f(c) with g(c) in-wave
        if ((lane & 31) == 0) {
            float f = act, gv = other;
            float h_old = hs[col];
            float hnew = fmaf(f, h_old - gv, gv);
            asm volatile("s_waitcnt vmcnt(0)" ::: "memory"); // clear store acked
            __hip_atomic_store((unsigned*)(hb + (size_t)bn * 8192 + col),
                               __builtin_bit_cast(unsigned, hnew),
                               __ATOMIC_RELAXED, __HIP_MEMORY_SCOPE_AGENT);
            H[prow + (size_t)t * Cv] = f2bf(hnew);
        }
        int tmp = bc; bc = bn; bn = bx; bx = tmp;
    }
}

// ---------------- host launch ----------------
extern "C" void kernel_launch(void* const* d_in, const int* in_sizes, int n_in,
                              void* d_out, int out_size, void* d_ws, size_t ws_size,
                              hipStream_t stream) {
    const float* x  = (const float*)d_in[0];
    const float* Wf = (const float*)d_in[1];
    const float* Wg = (const float*)d_in[2];
    const float* Wp = (const float*)d_in[3];
    float* out = (float*)d_out;
    char* ws = (char*)d_ws;

    // workspace layout (bytes)
    u16*   xb    = (u16*)(ws + 0);          // 33554432 (dead after the two P-gemms)
    u16*   Pf    = (u16*)(ws + 33554432);   // 33554432
    u16*   Pg    = (u16*)(ws + 67108864);   // 33554432
    u16*   Hb    = (u16*)(ws + 100663296);  // 33554432
    u16*   WfT   = (u16*)(ws + 134217728);  // 2097152
    u16*   WgT   = (u16*)(ws + 136314880);  // 2097152
    u16*   WpT   = (u16*)(ws + 138412032);  // 2097152
    // h triple-buffer reuses the (dead) xb region: 3 x 8 x 1024 fp32 = 98304 B
    float* hbuf  = (float*)(ws + 0);

    cvt_x<<<16384, 256, 0, stream>>>(x, xb, (Bv * Tv * Cv) / 4);

    dim3 tg(32, 32), tb(32, 8);
    transpose_cvt<<<tg, tb, 0, stream>>>(Wf, WfT); // top half rows of W_f
    transpose_cvt<<<tg, tb, 0, stream>>>(Wg, WgT);
    transpose_cvt<<<tg, tb, 0, stream>>>(Wp, WpT);

    gemm_bt<true><<<1024, 256, 0, stream>>>(xb, WfT, (void*)Pf, Bv * Tv, Cv, Cv);
    gemm_bt<true><<<1024, 256, 0, stream>>>(xb, WgT, (void*)Pg, Bv * Tv, Cv, Cv);

    // xb now dead; initialize h triple-buffer in its place
    init_hbuf<<<24, 1024, 0, stream>>>((unsigned*)hbuf);

    {
        const float* a0 = Wf;
        const float* a1 = Wg;
        const u16* a2 = Pf;
        const u16* a3 = Pg;
        u16* a4 = Hb;
        float* a5 = hbuf;
        void* args[] = {(void*)&a0, (void*)&a1, (void*)&a2, (void*)&a3,
                        (void*)&a4, (void*)&a5};
        hipLaunchCooperativeKernel((const void*)cfc_scan, dim3(256), dim3(1024), args, 0, stream);
    }

    gemm_bt<false><<<1024, 256, 0, stream>>>(Hb, WpT, (void*)out, Bv * Tv, Cv, Cv);
}